// Round 1
// baseline (677.599 us; speedup 1.0000x reference)
//
#include <hip/hip_runtime.h>
#include <math.h>

#define B_DIM 256
#define P_DIM 4
#define N_DIM 1024
#define D_DIM 512
#define NV (P_DIM + N_DIM)   // 1028 sims per row
#define INV_TEMP 10.0f       // 1 / 0.1
#define POS_W 0.3f
#define EPS_C 1e-8f
#define VPW 4                // vectors per wave in sims_kernel
#define VBLK 65              // ceil(1028 / (4 waves * VPW)) = 65 blocks per row

__device__ __forceinline__ float wave_sum_f(float v) {
#pragma unroll
  for (int m = 1; m < 64; m <<= 1) v += __shfl_xor(v, m, 64);
  return v;
}

__device__ __forceinline__ float wave_max_f(float v) {
#pragma unroll
  for (int m = 1; m < 64; m <<= 1) v = fmaxf(v, __shfl_xor(v, m, 64));
  return v;
}

__device__ __forceinline__ int wave_sum_i(int v) {
#pragma unroll
  for (int m = 1; m < 64; m <<= 1) v += __shfl_xor(v, m, 64);
  return v;
}

__device__ __forceinline__ float dot4(float4 a, float4 b) {
  return a.x * b.x + a.y * b.y + a.z * b.z + a.w * b.w;
}

// ---------------------------------------------------------------------------
// Kernel 1: streaming cosine sims. Pure BW kernel.
// grid = (VBLK, B), block = 256 threads = 4 waves, 32 waves/CU occupancy
// (VGPR capped to 64 via __launch_bounds__(256, 8)).
// Each wave handles 4 consecutive vectors (two pairs), lane-parallel over D.
// v0 is always a multiple of 4 and NV = 1028 = 4*257, so a wave has either
// 4 valid vectors or none (tail block's waves 1..3 exit early; no barriers).
// ---------------------------------------------------------------------------
__global__ __launch_bounds__(256, 8) void sims_kernel(
    const float* __restrict__ anchor, const float* __restrict__ positives,
    const float* __restrict__ negatives, float* __restrict__ simsg) {
  const int b = blockIdx.y;
  const int lane = threadIdx.x & 63;
  const int wave = threadIdx.x >> 6;
  const int v0 = blockIdx.x * (4 * VPW) + wave * VPW;
  if (v0 >= NV) return;

  const float4* arow = (const float4*)(anchor + (size_t)b * D_DIM);
  const float4 a0 = arow[lane];
  const float4 a1 = arow[lane + 64];

  const float* posrow = positives + (size_t)b * P_DIM * D_DIM;
  const float* negrow = negatives + (size_t)b * N_DIM * D_DIM;

  float asq = dot4(a0, a0) + dot4(a1, a1);
  asq = wave_sum_f(asq);
  const float anorm = sqrtf(asq);

  float out[VPW];
#pragma unroll
  for (int pr = 0; pr < VPW / 2; ++pr) {
    const int va = v0 + 2 * pr;
    const int vb = va + 1;
    const float4* pa = (const float4*)((va < P_DIM)
                           ? posrow + (size_t)va * D_DIM
                           : negrow + (size_t)(va - P_DIM) * D_DIM);
    const float4* pb = (const float4*)((vb < P_DIM)
                           ? posrow + (size_t)vb * D_DIM
                           : negrow + (size_t)(vb - P_DIM) * D_DIM);
    // Pair A loads
    const float4 x0 = pa[lane];
    const float4 x1 = pa[lane + 64];
    float da = dot4(a0, x0) + dot4(a1, x1);
    float qa = dot4(x0, x0) + dot4(x1, x1);
    // Pair B loads issued before A's shuffle reduction so they overlap it.
    const float4 y0 = pb[lane];
    const float4 y1 = pb[lane + 64];
    da = wave_sum_f(da);
    qa = wave_sum_f(qa);
    float db = dot4(a0, y0) + dot4(a1, y1);
    float qb = dot4(y0, y0) + dot4(y1, y1);
    db = wave_sum_f(db);
    qb = wave_sum_f(qb);
    out[2 * pr]     = da / fmaxf(anorm * sqrtf(qa), EPS_C);
    out[2 * pr + 1] = db / fmaxf(anorm * sqrtf(qb), EPS_C);
  }

  // One float4 store per wave. Row base b*1028 floats = 4112 B (16B-aligned)
  // and v0 is a multiple of 4, so the address is 16B-aligned.
  if (lane == 0) {
    *(float4*)(simsg + (size_t)b * NV + v0) =
        make_float4(out[0], out[1], out[2], out[3]);
  }
}

// ---------------------------------------------------------------------------
// Kernel 2: per-row softmax + stable-rank. One wave per row; the 1028 sims
// are loaded once into 17 registers/lane, all passes are register passes.
// ---------------------------------------------------------------------------
__global__ __launch_bounds__(64) void rank_kernel(
    const float* __restrict__ simsg, float* __restrict__ partials) {
  const int b = blockIdx.x;
  const int lane = threadIdx.x;
  const float* row = simsg + (size_t)b * NV;

  float s[17];
#pragma unroll
  for (int k = 0; k < 17; ++k) {
    const int v = lane + 64 * k;
    s[k] = (v < NV) ? row[v] : -3.4e38f;  // sentinel; sims are in [-1,1]
  }

  float m = -3.4e38f;
#pragma unroll
  for (int k = 0; k < 17; ++k) m = fmaxf(m, s[k] * INV_TEMP);
  m = wave_max_f(m);

  float Z = 0.0f;
#pragma unroll
  for (int k = 0; k < 17; ++k) Z += expf(s[k] * INV_TEMP - m);  // sentinel -> exp(-inf)=0
  Z = wave_sum_f(Z);

  // sims[0..3] live in lanes 0..3 of s[0]
  const float sp0 = __shfl(s[0], 0, 64);
  const float sp1 = __shfl(s[0], 1, 64);
  const float sp2 = __shfl(s[0], 2, 64);
  const float sp3 = __shfl(s[0], 3, 64);

  int c0 = 0, c1 = 0, c2 = 0, c3 = 0;
#pragma unroll
  for (int k = 0; k < 17; ++k) {
    const int v = lane + 64 * k;
    const float sv = s[k];  // sentinel can't be > or == any sim in [-1,1]
    c0 += (sv > sp0);
    c1 += (sv > sp1) || (sv == sp1 && v < 1);
    c2 += (sv > sp2) || (sv == sp2 && v < 2);
    c3 += (sv > sp3) || (sv == sp3 && v < 3);
  }
  c0 = wave_sum_i(c0);
  c1 = wave_sum_i(c1);
  c2 = wave_sum_i(c2);
  c3 = wave_sum_i(c3);

  if (lane == 0) {
    const float invZ = 1.0f / Z;
    const float p0 = expf(sp0 * INV_TEMP - m) * invZ;
    const float p1 = expf(sp1 * INV_TEMP - m) * invZ;
    const float p2 = expf(sp2 * INV_TEMP - m) * invZ;
    const float p3 = expf(sp3 * INV_TEMP - m) * invZ;
    const float err = p0 / (float)(c0 + 1) + p1 / (float)(c1 + 1) +
                      p2 / (float)(c2 + 1) + p3 / (float)(c3 + 1);
    partials[b] = err;
    partials[B_DIM + b] = sp0 + sp1 + sp2 + sp3;
  }
}

__global__ __launch_bounds__(256) void rr_finalize_kernel(
    const float* __restrict__ partials, float* __restrict__ out) {
  const int t = threadIdx.x;
  const int lane = t & 63;
  const int wave = t >> 6;
  float rr = partials[t];
  float ps = partials[B_DIM + t];
  rr = wave_sum_f(rr);
  ps = wave_sum_f(ps);
  __shared__ float srr[4], sps[4];
  if (lane == 0) { srr[wave] = rr; sps[wave] = ps; }
  __syncthreads();
  if (t == 0) {
    const float SRR = srr[0] + srr[1] + srr[2] + srr[3];
    const float SPS = sps[0] + sps[1] + sps[2] + sps[3];
    const float loss =
        -(SRR / (float)B_DIM) +
        POS_W * (1.0f - SPS / (float)(B_DIM * P_DIM));
    out[0] = loss;
  }
}

extern "C" void kernel_launch(void* const* d_in, const int* in_sizes, int n_in,
                              void* d_out, int out_size, void* d_ws, size_t ws_size,
                              hipStream_t stream) {
  const float* anchor = (const float*)d_in[0];
  const float* positives = (const float*)d_in[1];
  const float* negatives = (const float*)d_in[2];
  float* simsg = (float*)d_ws;                          // 256*1028 floats = 1.05 MB
  float* partials = (float*)d_ws + (size_t)B_DIM * NV;  // 512 floats
  float* out = (float*)d_out;

  sims_kernel<<<dim3(VBLK, B_DIM), 256, 0, stream>>>(anchor, positives,
                                                     negatives, simsg);
  rank_kernel<<<B_DIM, 64, 0, stream>>>(simsg, partials);
  rr_finalize_kernel<<<1, 256, 0, stream>>>(partials, out);
}